// Round 5
// baseline (571.803 us; speedup 1.0000x reference)
//
#include <hip/hip_runtime.h>
#include <math.h>

#define T_   50
#define B_   2048
#define NS_  12
#define NC_  4
#define NSC_ 16
#define LDC  20          // padded LDS row stride (riccati kernel only)
#define TAUS_STRIDE 808  // per-alpha stride for tau trajectories (50*16=800, +8 pad)

__device__ __forceinline__ float dot4f(const float4 a, const float4 b) {
    return a.x*b.x + a.y*b.y + a.z*b.z + a.w*b.w;
}
__device__ __forceinline__ void axpy4(float4& acc, float s, const float4 v) {
    acc.x += s*v.x; acc.y += s*v.y; acc.z += s*v.z; acc.w += s*v.w;
}

// Wave-local sync (single-wave ordering). Drains lgkmcnt only; vmcnt stays
// in flight. 0xC07F = vmcnt(63) expcnt(7) lgkmcnt(0).
__device__ __forceinline__ void wsync() {
    __builtin_amdgcn_wave_barrier();
    __builtin_amdgcn_s_waitcnt(0xC07F);
    __builtin_amdgcn_wave_barrier();
}

// Cross-wave barrier: drains LDS (lgkmcnt) but NOT vmcnt, so prefetched
// global loads stay in flight across it. Built from builtins (no asm
// "memory" clobber — that forces a vmcnt(0) drain, the Round-3 regression).
// Verified passing in Round 4.
__device__ __forceinline__ void bsync() {
    __builtin_amdgcn_wave_barrier();
    __builtin_amdgcn_s_waitcnt(0xC07F);   // lgkmcnt(0) only
    __builtin_amdgcn_s_barrier();
    __builtin_amdgcn_wave_barrier();
}

// ---------------------------------------------------------------------------
// Kernel 1: backward Riccati recursion. One 64-lane wave per batch element.
// (unchanged this round — isolate the rollout change for attribution)
// ---------------------------------------------------------------------------
struct RicPref { float4 rC, rAux; };

__device__ __forceinline__ RicPref ric_load(
    const float* Cg, const float* cg, const float* Fg, const float* fg,
    int t, int b, int lane)
{
    RicPref p;
    const size_t base = (size_t)t * B_ + b;
    p.rC = ((const float4*)(Cg + base*256))[lane];
    if (lane < 48)      p.rAux = ((const float4*)(Fg + base*192))[lane];
    else if (lane < 52) p.rAux = ((const float4*)(cg + base*16))[lane-48];
    else if (lane < 55) p.rAux = ((const float4*)(fg + base*12))[lane-52];
    return p;
}

__global__ __launch_bounds__(64) void riccati_kernel(
    const float* __restrict__ Cg, const float* __restrict__ cg,
    const float* __restrict__ Fg, const float* __restrict__ fg,
    float* __restrict__ Kk)
{
    const int b    = blockIdx.x;
    const int lane = threadIdx.x;

    __shared__ __align__(16) float sV[144];      // V  12x12 (stride 12)
    __shared__ __align__(16) float sv[12];
    __shared__ __align__(16) float sF[12*LDC];   // F  12x16 (stride 20)
    __shared__ __align__(16) float sC[16*LDC];   // C  16x16 (stride 20)
    __shared__ __align__(16) float sc[16];
    __shared__ __align__(16) float sf[12];
    __shared__ __align__(16) float sP[12*LDC];   // P = V*F  12x16
    __shared__ __align__(16) float sQ[16*LDC];   // Q 16x16
    __shared__ __align__(16) float sq[16];
    __shared__ __align__(16) float stmp[12];     // V f + v
    __shared__ __align__(16) float sK[48];       // K 4x12 row-major
    __shared__ __align__(16) float skk[4];
    __shared__ __align__(16) float sM[144];      // M = K^T Qux  12x12 (stride 12)

    for (int i = lane; i < 144; i += 64) sV[i] = 0.f;
    if (lane < 12) sv[lane] = 0.f;

    RicPref cur = ric_load(Cg, cg, Fg, fg, T_-1, b, lane);
    wsync();

    for (int t = T_ - 1; t >= 0; --t) {
        const size_t base = (size_t)t * B_ + b;

        wsync();   // WAR: prior phases' LDS reads complete before overwrite
        {
            const int row = lane >> 2, ch = (lane & 3) << 2;
            *(float4*)(sC + row*LDC + ch) = cur.rC;
            if (lane < 48)      *(float4*)(sF + row*LDC + ch) = cur.rAux;
            else if (lane < 52) ((float4*)sc)[lane-48] = cur.rAux;
            else if (lane < 55) ((float4*)sf)[lane-52] = cur.rAux;
        }
        RicPref nxt = ric_load(Cg, cg, Fg, fg, (t > 0) ? t-1 : 0, b, lane);
        wsync();

        // ---- P = V * F (12x16); tmp = V f + v ----
        if (lane < 48) {
            const int k = lane >> 2, jc = (lane & 3) << 2;
            float4 acc = make_float4(0.f,0.f,0.f,0.f);
            #pragma unroll
            for (int l = 0; l < 12; ++l) {
                axpy4(acc, sV[k*12 + l], *(const float4*)(sF + l*LDC + jc));
            }
            *(float4*)(sP + k*LDC + jc) = acc;
        } else if (lane < 60) {
            const int k = lane - 48;
            float acc = sv[k];
            #pragma unroll
            for (int l = 0; l < 12; ++l) acc += sV[k*12 + l] * sf[l];
            stmp[k] = acc;
        }
        wsync();

        // ---- Q = C + F^T P (16x16); q = c + F^T tmp ----
        {
            const int i = lane >> 2, jc = (lane & 3) << 2;
            float4 acc = *(const float4*)(sC + i*LDC + jc);
            #pragma unroll
            for (int k = 0; k < 12; ++k) {
                axpy4(acc, sF[k*LDC + i], *(const float4*)(sP + k*LDC + jc));
            }
            *(float4*)(sQ + i*LDC + jc) = acc;
        }
        if (lane < 16) {
            float acc = sc[lane];
            #pragma unroll
            for (int k = 0; k < 12; ++k) acc += sF[k*LDC + lane] * stmp[k];
            sq[lane] = acc;
        }
        wsync();

        // ---- solve Quu * sol = [Qux | qu] via redundant 4x4 Cholesky ----
        {
            const float* Qu = sQ + 12*LDC + 12;
            const float a00=Qu[0],      a01=Qu[1],      a02=Qu[2],      a03=Qu[3];
            const float a11=Qu[LDC+1],  a12=Qu[LDC+2],  a13=Qu[LDC+3];
            const float a22=Qu[2*LDC+2],a23=Qu[2*LDC+3],a33=Qu[3*LDC+3];
            const float l00 = sqrtf(a00), i00 = 1.f/l00;
            const float l10 = a01*i00, l20 = a02*i00, l30 = a03*i00;
            const float l11 = sqrtf(a11 - l10*l10), i11 = 1.f/l11;
            const float l21 = (a12 - l20*l10)*i11;
            const float l31 = (a13 - l30*l10)*i11;
            const float l22 = sqrtf(a22 - l20*l20 - l21*l21), i22 = 1.f/l22;
            const float l32 = (a23 - l30*l20 - l31*l21)*i22;
            const float l33 = sqrtf(a33 - l30*l30 - l31*l31 - l32*l32), i33 = 1.f/l33;
            if (lane < 13) {   // one RHS column per lane
                float r0, r1, r2, r3;
                if (lane < 12) {
                    r0 = sQ[12*LDC + lane]; r1 = sQ[13*LDC + lane];
                    r2 = sQ[14*LDC + lane]; r3 = sQ[15*LDC + lane];
                } else {
                    r0 = sq[12]; r1 = sq[13]; r2 = sq[14]; r3 = sq[15];
                }
                const float y0 = r0*i00;
                const float y1 = (r1 - l10*y0)*i11;
                const float y2 = (r2 - l20*y0 - l21*y1)*i22;
                const float y3 = (r3 - l30*y0 - l31*y1 - l32*y2)*i33;
                const float z3 = y3*i33;
                const float z2 = (y2 - l32*z3)*i22;
                const float z1 = (y1 - l21*z2 - l31*z3)*i11;
                const float z0 = (y0 - l10*z1 - l20*z2 - l30*z3)*i00;
                if (lane < 12) {
                    sK[0*12+lane] = -z0; sK[1*12+lane] = -z1;
                    sK[2*12+lane] = -z2; sK[3*12+lane] = -z3;
                } else {
                    skk[0] = -z0; skk[1] = -z1; skk[2] = -z2; skk[3] = -z3;
                }
            }
        }
        wsync();

        // ---- emit K,kk; M = K^T Qux; v' = qx + Qxu kk ----
        if (lane < 52) {
            (Kk + base*52)[lane] = (lane < 48) ? sK[lane] : skk[lane-48];
        }
        if (lane < 36) {
            const int i = lane / 3, jc = (lane % 3) << 2;
            float4 acc = make_float4(0.f,0.f,0.f,0.f);
            #pragma unroll
            for (int m = 0; m < 4; ++m) {
                axpy4(acc, sK[m*12 + i], *(const float4*)(sQ + (12+m)*LDC + jc));
            }
            *(float4*)(sM + i*12 + jc) = acc;
        } else if (lane < 48) {
            const int i = lane - 36;
            float acc = sq[i];
            #pragma unroll
            for (int m = 0; m < 4; ++m) acc += sQ[i*LDC + 12 + m] * skk[m];
            sv[i] = acc;
        }
        wsync();

        // ---- V' = Qxx + 0.5(M + M^T) ----
        if (lane < 36) {
            const int i = lane / 3, jc = (lane % 3) << 2;
            const float4 q  = *(const float4*)(sQ + i*LDC + jc);
            const float4 m1 = *(const float4*)(sM + i*12 + jc);
            const float t0 = sM[(jc+0)*12 + i];
            const float t1 = sM[(jc+1)*12 + i];
            const float t2 = sM[(jc+2)*12 + i];
            const float t3 = sM[(jc+3)*12 + i];
            float4 r;
            r.x = q.x + 0.5f*(m1.x + t0);
            r.y = q.y + 0.5f*(m1.y + t1);
            r.z = q.z + 0.5f*(m1.z + t2);
            r.w = q.w + 0.5f*(m1.w + t3);
            *(float4*)(sV + i*12 + jc) = r;
        }
        cur = nxt;
    }
}

// ---------------------------------------------------------------------------
// Kernel 2: rollout v5 = v3 dataflow (matrix rows in per-lane registers from
// global; LDS holds only tau trajectory + unom) + v4's NON-draining bsync +
// named-register double buffer (no struct arrays — everything statically
// indexed, so the ping-pong provably lives in VGPRs).
// ---------------------------------------------------------------------------
__global__ __launch_bounds__(128, 4) void rollout_kernel(
    const float* __restrict__ x0g, const float* __restrict__ Cg,
    const float* __restrict__ cg,  const float* __restrict__ Fg,
    const float* __restrict__ fg,  const float* __restrict__ Kk,
    float* __restrict__ outg)
{
    const int b    = blockIdx.x;
    const int tid  = threadIdx.x;
    const int wave = tid >> 6;
    const int lane = tid & 63;

    __shared__ __align__(16) float staus[5*TAUS_STRIDE]; // [a][t][16]
    __shared__ __align__(16) float sunom[T_*NC_];        // [t][4]
    __shared__ __align__(16) float sx0[12];
    __shared__ float scost[5];
    __shared__ int   sbest;

    // ---------------- per-lane task constants (loop-invariant) ----------------
    // task = wave*64+lane: 0..79 cost (a=task>>4, i=task&15); 80..127 x_next
    // (v=task-80, a=v/12, i=v%12). wave0 = tasks 0..63 (all cost).
    const int  task    = wave*64 + lane;
    const bool is_cost = task < 80;
    int a1, i1;
    if (is_cost) { a1 = task >> 4; i1 = task & 15; }
    else { const int v = task - 80; a1 = v / 12; i1 = v - a1*12; }
    float* taub1 = staus + a1*TAUS_STRIDE;

    // wave0 tail: x_next alpha4, row iT (compute guarded lane<12; loads uniform)
    const int iT = (lane < 12) ? lane : 11;
    float* taubT = staus + 4*TAUS_STRIDE;

    // wave1 u-phase: a=lane>>2 (0..4), i=lane&3 (compute guarded lane<20)
    const int   aA  = (lane < 20) ? (lane >> 2) : 0;
    const int   iA  = lane & 3;
    const float alA = ldexpf(1.0f, -aA);   // 0.5^a
    float* tauA = staus + aA*TAUS_STRIDE;

    // ---- branch-free global row/scalar bases (floats) + per-step strides ----
    const float *rowB, *auxB, *s0B, *s1B;
    int rowS, auxS, s0S, s1S;
    if (wave == 0) {
        rowB = Cg + (size_t)b*256 + i1*16;  rowS = B_*256;   // C row i1
        s0B  = cg + (size_t)b*16  + i1;     s0S  = B_*16;    // c[i1]
        auxB = Fg + (size_t)b*192 + iT*16;  auxS = B_*192;   // F row iT (tail)
        s1B  = fg + (size_t)b*12  + iT;     s1S  = B_*12;    // f[iT]
    } else {
        if (is_cost) { rowB = Cg + (size_t)b*256 + i1*16; rowS = B_*256;
                       s0B  = cg + (size_t)b*16  + i1;    s0S  = B_*16; }
        else         { rowB = Fg + (size_t)b*192 + i1*16; rowS = B_*192;
                       s0B  = fg + (size_t)b*12  + i1;    s0S  = B_*12; }
        auxB = Kk + (size_t)b*52 + iA*12;   auxS = B_*52;    // K row iA (+kk tail, in-bounds)
        s1B  = Kk + (size_t)b*52 + 48 + iA; s1S  = B_*52;    // kk[iA]
    }

    // ---------------- named double-buffer registers ----------------
    float4 Xr0,Xr1,Xr2,Xr3, Xa0,Xa1,Xa2,Xa3; float Xs0,Xs1;   // buffer X
    float4 Yr0,Yr1,Yr2,Yr3, Ya0,Ya1,Ya2,Ya3; float Ys0,Ys1;   // buffer Y

    auto loadX = [&](int tn) {
        const float* rp = rowB + (size_t)tn*rowS;
        Xr0 = *(const float4*)(rp);    Xr1 = *(const float4*)(rp+4);
        Xr2 = *(const float4*)(rp+8);  Xr3 = *(const float4*)(rp+12);
        const float* ap = auxB + (size_t)tn*auxS;
        Xa0 = *(const float4*)(ap);    Xa1 = *(const float4*)(ap+4);
        Xa2 = *(const float4*)(ap+8);  Xa3 = *(const float4*)(ap+12);
        Xs0 = s0B[(size_t)tn*s0S];     Xs1 = s1B[(size_t)tn*s1S];
    };
    auto loadY = [&](int tn) {
        const float* rp = rowB + (size_t)tn*rowS;
        Yr0 = *(const float4*)(rp);    Yr1 = *(const float4*)(rp+4);
        Yr2 = *(const float4*)(rp+8);  Yr3 = *(const float4*)(rp+12);
        const float* ap = auxB + (size_t)tn*auxS;
        Ya0 = *(const float4*)(ap);    Ya1 = *(const float4*)(ap+4);
        Ya2 = *(const float4*)(ap+8);  Ya3 = *(const float4*)(ap+12);
        Ys0 = s0B[(size_t)tn*s0S];     Ys1 = s1B[(size_t)tn*s1S];
    };

    // step body for data(t) held in the given registers. Call AFTER bsync (B1)
    // and after issuing next-step loads. Contains B2 internally.
    auto body = [&](float4 r0, float4 r1, float4 r2, float4 r3,
                    float4 a0, float4 a1, float4 a2, float4 a3,
                    float s0, float s1, int t, int toff, float& ca) {
        // u-phase (wave1, lanes<20): u(t) from K(t) regs + x(t) in LDS
        if (wave == 1 && lane < 20) {
            const float* xp = tauA + toff;
            float ulqr = dot4f(a0, *(const float4*)(xp))
                       + dot4f(a1, *(const float4*)(xp+4))
                       + dot4f(a2, *(const float4*)(xp+8))
                       + s1;
            float u = (1.f - alA)*sunom[t*4 + iA] + alA*ulqr;
            u = fminf(1.f, fmaxf(-1.f, u));
            tauA[toff + 12 + iA] = u;
        }

        // pre-B2 partial: x-part of the dot (x(t) published at B1)
        const float* tp = taub1 + toff;
        float acc = is_cost ? 0.f : s0;        // x_next starts at f_i (order-exact)
        acc += dot4f(r0, *(const float4*)(tp));
        acc += dot4f(r1, *(const float4*)(tp+4));
        acc += dot4f(r2, *(const float4*)(tp+8));

        float accT = 0.f;
        if (wave == 0 && lane < 12) {          // tail pre-partial (alpha4 x_next)
            const float* tq = taubT + toff;
            accT = s1;
            accT += dot4f(a0, *(const float4*)(tq));
            accT += dot4f(a1, *(const float4*)(tq+4));
            accT += dot4f(a2, *(const float4*)(tq+8));
        }

        bsync();                               // B2: u(t) published

        acc += dot4f(r3, *(const float4*)(taub1 + toff + 12));
        const bool tnl = (t != T_-1);
        if (is_cost) {
            ca += (0.5f*acc + s0) * taub1[toff + i1];
        } else if (tnl) {
            taub1[toff + 16 + i1] = acc;       // x(t+1)
        }
        if (wave == 0 && lane < 12 && tnl) {
            accT += dot4f(a3, *(const float4*)(taubT + toff + 12));
            taubT[toff + 16 + iT] = accT;
        }
    };

    // ---------------- prologue ----------------
    for (int i = tid; i < T_*NC_; i += 128) sunom[i] = 0.f;
    if (tid < 3) ((float4*)sx0)[tid] = ((const float4*)(x0g + (size_t)b*12))[tid];

    loadX(0);
    bsync();

    for (int iter = 0; iter < 3; ++iter) {
        // x(0) = x0 into row 0 of every alpha's trajectory
        if (tid < 15) {
            const int a = tid / 3, ch = (tid % 3) << 2;
            *(float4*)(staus + a*TAUS_STRIDE + ch) = *(const float4*)(sx0 + ch);
        }
        float ca = 0.f;   // wave0: alphas 0-3 (16-lane groups); wave1 lanes<16: alpha4

        for (int t = 0; t < T_; t += 2) {
            // step t: consume X, prefetch t+1 into Y
            bsync();                                   // B1
            loadY(t+1 < T_ ? t+1 : 0);
            body(Xr0,Xr1,Xr2,Xr3, Xa0,Xa1,Xa2,Xa3, Xs0,Xs1, t,   t*16,    ca);
            // step t+1: consume Y, prefetch t+2 into X (wraps to 0 at iter end)
            bsync();                                   // B1
            loadX(t+2 < T_ ? t+2 : 0);
            body(Yr0,Yr1,Yr2,Yr3, Ya0,Ya1,Ya2,Ya3, Ys0,Ys1, t+1, t*16+16, ca);
        }
        // T_=50 even: X again holds t=0 data for the next iteration

        // ---- reduce costs (16-lane groups), select best alpha ----
        #pragma unroll
        for (int off = 1; off < 16; off <<= 1) ca += __shfl_xor(ca, off, 16);
        if (wave == 0) { if ((lane & 15) == 0) scost[lane >> 4] = ca; }
        else if (lane == 0) scost[4] = ca;
        bsync();
        if (tid == 0) {
            int bi = 0; float bc = scost[0];
            #pragma unroll
            for (int a = 1; a < 5; ++a) {
                if (scost[a] < bc) { bc = scost[a]; bi = a; }  // first-min = jnp.argmin
            }
            sbest = bi;
        }
        bsync();
        const int best = sbest;

        // ---- u_nom <- best trajectory's u; final iter: write taus out ----
        for (int idx = tid; idx < T_*NC_; idx += 128) {
            const int tt = idx >> 2, i = idx & 3;
            sunom[idx] = staus[best*TAUS_STRIDE + tt*16 + 12 + i];
        }
        if (iter == 2) {
            for (int idx = tid; idx < T_*NSC_; idx += 128) {
                const int tt = idx >> 4, j = idx & 15;
                outg[((size_t)tt*B_ + b)*16 + j] = staus[best*TAUS_STRIDE + tt*16 + j];
            }
        }
        bsync();
    } // iter
}

extern "C" void kernel_launch(void* const* d_in, const int* in_sizes, int n_in,
                              void* d_out, int out_size, void* d_ws, size_t ws_size,
                              hipStream_t stream) {
    const float* x0 = (const float*)d_in[0];
    const float* C  = (const float*)d_in[1];
    const float* c  = (const float*)d_in[2];
    const float* F  = (const float*)d_in[3];
    const float* f  = (const float*)d_in[4];
    float* out = (float*)d_out;
    float* Kk  = (float*)d_ws;   // needs 50*2048*52*4 = 21.3 MB

    riccati_kernel<<<B_, 64, 0, stream>>>(C, c, F, f, Kk);
    rollout_kernel<<<B_, 128, 0, stream>>>(x0, C, c, F, f, Kk, out);
}

// Round 6
// 570.611 us; speedup vs baseline: 1.0021x; 1.0021x over previous
//
#include <hip/hip_runtime.h>
#include <math.h>

#define T_   50
#define B_   2048
#define NS_  12
#define NC_  4
#define NSC_ 16
#define LDC  20          // padded LDS row stride (riccati kernel only)
#define TAUS_STRIDE 808  // per-alpha stride for tau trajectories (50*16=800, +8 pad)

__device__ __forceinline__ float dot4f(const float4 a, const float4 b) {
    return a.x*b.x + a.y*b.y + a.z*b.z + a.w*b.w;
}
__device__ __forceinline__ void axpy4(float4& acc, float s, const float4 v) {
    acc.x += s*v.x; acc.y += s*v.y; acc.z += s*v.z; acc.w += s*v.w;
}

// Wave-local sync (single-wave ordering). Drains lgkmcnt only; vmcnt stays
// in flight. 0xC07F = vmcnt(63) expcnt(7) lgkmcnt(0).
__device__ __forceinline__ void wsync() {
    __builtin_amdgcn_wave_barrier();
    __builtin_amdgcn_s_waitcnt(0xC07F);
    __builtin_amdgcn_wave_barrier();
}

// Cross-wave barrier: drains LDS (lgkmcnt) but NOT vmcnt, so prefetched
// global loads stay in flight across it. Built from builtins (no asm
// "memory" clobber — that forces a vmcnt(0) drain, the Round-3 regression).
// Verified passing in Rounds 4 and 5.
__device__ __forceinline__ void bsync() {
    __builtin_amdgcn_wave_barrier();
    __builtin_amdgcn_s_waitcnt(0xC07F);   // lgkmcnt(0) only
    __builtin_amdgcn_s_barrier();
    __builtin_amdgcn_wave_barrier();
}

// ---------------------------------------------------------------------------
// Kernel 1: backward Riccati recursion. One 64-lane wave per batch element.
// (unchanged this round — isolate the rollout change for attribution)
// ---------------------------------------------------------------------------
struct RicPref { float4 rC, rAux; };

__device__ __forceinline__ RicPref ric_load(
    const float* Cg, const float* cg, const float* Fg, const float* fg,
    int t, int b, int lane)
{
    RicPref p;
    const size_t base = (size_t)t * B_ + b;
    p.rC = ((const float4*)(Cg + base*256))[lane];
    if (lane < 48)      p.rAux = ((const float4*)(Fg + base*192))[lane];
    else if (lane < 52) p.rAux = ((const float4*)(cg + base*16))[lane-48];
    else if (lane < 55) p.rAux = ((const float4*)(fg + base*12))[lane-52];
    return p;
}

__global__ __launch_bounds__(64) void riccati_kernel(
    const float* __restrict__ Cg, const float* __restrict__ cg,
    const float* __restrict__ Fg, const float* __restrict__ fg,
    float* __restrict__ Kk)
{
    const int b    = blockIdx.x;
    const int lane = threadIdx.x;

    __shared__ __align__(16) float sV[144];      // V  12x12 (stride 12)
    __shared__ __align__(16) float sv[12];
    __shared__ __align__(16) float sF[12*LDC];   // F  12x16 (stride 20)
    __shared__ __align__(16) float sC[16*LDC];   // C  16x16 (stride 20)
    __shared__ __align__(16) float sc[16];
    __shared__ __align__(16) float sf[12];
    __shared__ __align__(16) float sP[12*LDC];   // P = V*F  12x16
    __shared__ __align__(16) float sQ[16*LDC];   // Q 16x16
    __shared__ __align__(16) float sq[16];
    __shared__ __align__(16) float stmp[12];     // V f + v
    __shared__ __align__(16) float sK[48];       // K 4x12 row-major
    __shared__ __align__(16) float skk[4];
    __shared__ __align__(16) float sM[144];      // M = K^T Qux  12x12 (stride 12)

    for (int i = lane; i < 144; i += 64) sV[i] = 0.f;
    if (lane < 12) sv[lane] = 0.f;

    RicPref cur = ric_load(Cg, cg, Fg, fg, T_-1, b, lane);
    wsync();

    for (int t = T_ - 1; t >= 0; --t) {
        const size_t base = (size_t)t * B_ + b;

        wsync();   // WAR: prior phases' LDS reads complete before overwrite
        {
            const int row = lane >> 2, ch = (lane & 3) << 2;
            *(float4*)(sC + row*LDC + ch) = cur.rC;
            if (lane < 48)      *(float4*)(sF + row*LDC + ch) = cur.rAux;
            else if (lane < 52) ((float4*)sc)[lane-48] = cur.rAux;
            else if (lane < 55) ((float4*)sf)[lane-52] = cur.rAux;
        }
        RicPref nxt = ric_load(Cg, cg, Fg, fg, (t > 0) ? t-1 : 0, b, lane);
        wsync();

        // ---- P = V * F (12x16); tmp = V f + v ----
        if (lane < 48) {
            const int k = lane >> 2, jc = (lane & 3) << 2;
            float4 acc = make_float4(0.f,0.f,0.f,0.f);
            #pragma unroll
            for (int l = 0; l < 12; ++l) {
                axpy4(acc, sV[k*12 + l], *(const float4*)(sF + l*LDC + jc));
            }
            *(float4*)(sP + k*LDC + jc) = acc;
        } else if (lane < 60) {
            const int k = lane - 48;
            float acc = sv[k];
            #pragma unroll
            for (int l = 0; l < 12; ++l) acc += sV[k*12 + l] * sf[l];
            stmp[k] = acc;
        }
        wsync();

        // ---- Q = C + F^T P (16x16); q = c + F^T tmp ----
        {
            const int i = lane >> 2, jc = (lane & 3) << 2;
            float4 acc = *(const float4*)(sC + i*LDC + jc);
            #pragma unroll
            for (int k = 0; k < 12; ++k) {
                axpy4(acc, sF[k*LDC + i], *(const float4*)(sP + k*LDC + jc));
            }
            *(float4*)(sQ + i*LDC + jc) = acc;
        }
        if (lane < 16) {
            float acc = sc[lane];
            #pragma unroll
            for (int k = 0; k < 12; ++k) acc += sF[k*LDC + lane] * stmp[k];
            sq[lane] = acc;
        }
        wsync();

        // ---- solve Quu * sol = [Qux | qu] via redundant 4x4 Cholesky ----
        {
            const float* Qu = sQ + 12*LDC + 12;
            const float a00=Qu[0],      a01=Qu[1],      a02=Qu[2],      a03=Qu[3];
            const float a11=Qu[LDC+1],  a12=Qu[LDC+2],  a13=Qu[LDC+3];
            const float a22=Qu[2*LDC+2],a23=Qu[2*LDC+3],a33=Qu[3*LDC+3];
            const float l00 = sqrtf(a00), i00 = 1.f/l00;
            const float l10 = a01*i00, l20 = a02*i00, l30 = a03*i00;
            const float l11 = sqrtf(a11 - l10*l10), i11 = 1.f/l11;
            const float l21 = (a12 - l20*l10)*i11;
            const float l31 = (a13 - l30*l10)*i11;
            const float l22 = sqrtf(a22 - l20*l20 - l21*l21), i22 = 1.f/l22;
            const float l32 = (a23 - l30*l20 - l31*l21)*i22;
            const float l33 = sqrtf(a33 - l30*l30 - l31*l31 - l32*l32), i33 = 1.f/l33;
            if (lane < 13) {   // one RHS column per lane
                float r0, r1, r2, r3;
                if (lane < 12) {
                    r0 = sQ[12*LDC + lane]; r1 = sQ[13*LDC + lane];
                    r2 = sQ[14*LDC + lane]; r3 = sQ[15*LDC + lane];
                } else {
                    r0 = sq[12]; r1 = sq[13]; r2 = sq[14]; r3 = sq[15];
                }
                const float y0 = r0*i00;
                const float y1 = (r1 - l10*y0)*i11;
                const float y2 = (r2 - l20*y0 - l21*y1)*i22;
                const float y3 = (r3 - l30*y0 - l31*y1 - l32*y2)*i33;
                const float z3 = y3*i33;
                const float z2 = (y2 - l32*z3)*i22;
                const float z1 = (y1 - l21*z2 - l31*z3)*i11;
                const float z0 = (y0 - l10*z1 - l20*z2 - l30*z3)*i00;
                if (lane < 12) {
                    sK[0*12+lane] = -z0; sK[1*12+lane] = -z1;
                    sK[2*12+lane] = -z2; sK[3*12+lane] = -z3;
                } else {
                    skk[0] = -z0; skk[1] = -z1; skk[2] = -z2; skk[3] = -z3;
                }
            }
        }
        wsync();

        // ---- emit K,kk; M = K^T Qux; v' = qx + Qxu kk ----
        if (lane < 52) {
            (Kk + base*52)[lane] = (lane < 48) ? sK[lane] : skk[lane-48];
        }
        if (lane < 36) {
            const int i = lane / 3, jc = (lane % 3) << 2;
            float4 acc = make_float4(0.f,0.f,0.f,0.f);
            #pragma unroll
            for (int m = 0; m < 4; ++m) {
                axpy4(acc, sK[m*12 + i], *(const float4*)(sQ + (12+m)*LDC + jc));
            }
            *(float4*)(sM + i*12 + jc) = acc;
        } else if (lane < 48) {
            const int i = lane - 36;
            float acc = sq[i];
            #pragma unroll
            for (int m = 0; m < 4; ++m) acc += sQ[i*LDC + 12 + m] * skk[m];
            sv[i] = acc;
        }
        wsync();

        // ---- V' = Qxx + 0.5(M + M^T) ----
        if (lane < 36) {
            const int i = lane / 3, jc = (lane % 3) << 2;
            const float4 q  = *(const float4*)(sQ + i*LDC + jc);
            const float4 m1 = *(const float4*)(sM + i*12 + jc);
            const float t0 = sM[(jc+0)*12 + i];
            const float t1 = sM[(jc+1)*12 + i];
            const float t2 = sM[(jc+2)*12 + i];
            const float t3 = sM[(jc+3)*12 + i];
            float4 r;
            r.x = q.x + 0.5f*(m1.x + t0);
            r.y = q.y + 0.5f*(m1.y + t1);
            r.z = q.z + 0.5f*(m1.z + t2);
            r.w = q.w + 0.5f*(m1.w + t3);
            *(float4*)(sV + i*12 + jc) = r;
        }
        cur = nxt;
    }
}

// ---------------------------------------------------------------------------
// Kernel 2: rollout v6 = v5 dataflow (matrix rows in per-lane registers from
// global; LDS holds only tau trajectory + unom; non-draining bsync) with the
// register-residency fix: amdgpu_waves_per_eu(4,4). The grid caps occupancy
// at 4 waves/EU (2048 blocks / 256 CU x 2 waves), so telling the scheduler
// max=4 removes its incentive to shrink to 64 VGPRs — which in v5 made it
// sink the prefetch loads to their uses (VGPR_Count=64 < the 68 the double
// buffer needs) and exposed a full memory round trip every step.
// ---------------------------------------------------------------------------
__global__ __launch_bounds__(128) __attribute__((amdgpu_waves_per_eu(4, 4)))
void rollout_kernel(
    const float* __restrict__ x0g, const float* __restrict__ Cg,
    const float* __restrict__ cg,  const float* __restrict__ Fg,
    const float* __restrict__ fg,  const float* __restrict__ Kk,
    float* __restrict__ outg)
{
    const int b    = blockIdx.x;
    const int tid  = threadIdx.x;
    const int wave = tid >> 6;
    const int lane = tid & 63;

    __shared__ __align__(16) float staus[5*TAUS_STRIDE]; // [a][t][16]
    __shared__ __align__(16) float sunom[T_*NC_];        // [t][4]
    __shared__ __align__(16) float sx0[12];
    __shared__ float scost[5];
    __shared__ int   sbest;

    // ---------------- per-lane task constants (loop-invariant) ----------------
    // task = wave*64+lane: 0..79 cost (a=task>>4, i=task&15); 80..127 x_next
    // (v=task-80, a=v/12, i=v%12). wave0 = tasks 0..63 (all cost).
    const int  task    = wave*64 + lane;
    const bool is_cost = task < 80;
    int a1, i1;
    if (is_cost) { a1 = task >> 4; i1 = task & 15; }
    else { const int v = task - 80; a1 = v / 12; i1 = v - a1*12; }
    float* taub1 = staus + a1*TAUS_STRIDE;

    // wave0 tail: x_next alpha4, row iT (compute guarded lane<12; loads uniform)
    const int iT = (lane < 12) ? lane : 11;
    float* taubT = staus + 4*TAUS_STRIDE;

    // wave1 u-phase: a=lane>>2 (0..4), i=lane&3 (compute guarded lane<20)
    const int   aA  = (lane < 20) ? (lane >> 2) : 0;
    const int   iA  = lane & 3;
    const float alA = ldexpf(1.0f, -aA);   // 0.5^a
    float* tauA = staus + aA*TAUS_STRIDE;

    // ---- branch-free global row/scalar bases (floats) + per-step strides ----
    const float *rowB, *auxB, *s0B, *s1B;
    int rowS, auxS, s0S, s1S;
    if (wave == 0) {
        rowB = Cg + (size_t)b*256 + i1*16;  rowS = B_*256;   // C row i1
        s0B  = cg + (size_t)b*16  + i1;     s0S  = B_*16;    // c[i1]
        auxB = Fg + (size_t)b*192 + iT*16;  auxS = B_*192;   // F row iT (tail)
        s1B  = fg + (size_t)b*12  + iT;     s1S  = B_*12;    // f[iT]
    } else {
        if (is_cost) { rowB = Cg + (size_t)b*256 + i1*16; rowS = B_*256;
                       s0B  = cg + (size_t)b*16  + i1;    s0S  = B_*16; }
        else         { rowB = Fg + (size_t)b*192 + i1*16; rowS = B_*192;
                       s0B  = fg + (size_t)b*12  + i1;    s0S  = B_*12; }
        auxB = Kk + (size_t)b*52 + iA*12;   auxS = B_*52;    // K row iA (+kk tail, in-bounds)
        s1B  = Kk + (size_t)b*52 + 48 + iA; s1S  = B_*52;    // kk[iA]
    }

    // ---------------- named double-buffer registers ----------------
    float4 Xr0,Xr1,Xr2,Xr3, Xa0,Xa1,Xa2,Xa3; float Xs0,Xs1;   // buffer X
    float4 Yr0,Yr1,Yr2,Yr3, Ya0,Ya1,Ya2,Ya3; float Ys0,Ys1;   // buffer Y

    auto loadX = [&](int tn) {
        const float* rp = rowB + (size_t)tn*rowS;
        Xr0 = *(const float4*)(rp);    Xr1 = *(const float4*)(rp+4);
        Xr2 = *(const float4*)(rp+8);  Xr3 = *(const float4*)(rp+12);
        const float* ap = auxB + (size_t)tn*auxS;
        Xa0 = *(const float4*)(ap);    Xa1 = *(const float4*)(ap+4);
        Xa2 = *(const float4*)(ap+8);  Xa3 = *(const float4*)(ap+12);
        Xs0 = s0B[(size_t)tn*s0S];     Xs1 = s1B[(size_t)tn*s1S];
    };
    auto loadY = [&](int tn) {
        const float* rp = rowB + (size_t)tn*rowS;
        Yr0 = *(const float4*)(rp);    Yr1 = *(const float4*)(rp+4);
        Yr2 = *(const float4*)(rp+8);  Yr3 = *(const float4*)(rp+12);
        const float* ap = auxB + (size_t)tn*auxS;
        Ya0 = *(const float4*)(ap);    Ya1 = *(const float4*)(ap+4);
        Ya2 = *(const float4*)(ap+8);  Ya3 = *(const float4*)(ap+12);
        Ys0 = s0B[(size_t)tn*s0S];     Ys1 = s1B[(size_t)tn*s1S];
    };

    // step body for data(t) held in the given registers. Call AFTER bsync (B1)
    // and after issuing next-step loads. Contains B2 internally.
    auto body = [&](float4 r0, float4 r1, float4 r2, float4 r3,
                    float4 a0, float4 a1, float4 a2, float4 a3,
                    float s0, float s1, int t, int toff, float& ca) {
        // u-phase (wave1, lanes<20): u(t) from K(t) regs + x(t) in LDS
        if (wave == 1 && lane < 20) {
            const float* xp = tauA + toff;
            float ulqr = dot4f(a0, *(const float4*)(xp))
                       + dot4f(a1, *(const float4*)(xp+4))
                       + dot4f(a2, *(const float4*)(xp+8))
                       + s1;
            float u = (1.f - alA)*sunom[t*4 + iA] + alA*ulqr;
            u = fminf(1.f, fmaxf(-1.f, u));
            tauA[toff + 12 + iA] = u;
        }

        // pre-B2 partial: x-part of the dot (x(t) published at B1)
        const float* tp = taub1 + toff;
        float acc = is_cost ? 0.f : s0;        // x_next starts at f_i (order-exact)
        acc += dot4f(r0, *(const float4*)(tp));
        acc += dot4f(r1, *(const float4*)(tp+4));
        acc += dot4f(r2, *(const float4*)(tp+8));

        float accT = 0.f;
        if (wave == 0 && lane < 12) {          // tail pre-partial (alpha4 x_next)
            const float* tq = taubT + toff;
            accT = s1;
            accT += dot4f(a0, *(const float4*)(tq));
            accT += dot4f(a1, *(const float4*)(tq+4));
            accT += dot4f(a2, *(const float4*)(tq+8));
        }

        bsync();                               // B2: u(t) published

        acc += dot4f(r3, *(const float4*)(taub1 + toff + 12));
        const bool tnl = (t != T_-1);
        if (is_cost) {
            ca += (0.5f*acc + s0) * taub1[toff + i1];
        } else if (tnl) {
            taub1[toff + 16 + i1] = acc;       // x(t+1)
        }
        if (wave == 0 && lane < 12 && tnl) {
            accT += dot4f(a3, *(const float4*)(taubT + toff + 12));
            taubT[toff + 16 + iT] = accT;
        }
    };

    // ---------------- prologue ----------------
    for (int i = tid; i < T_*NC_; i += 128) sunom[i] = 0.f;
    if (tid < 3) ((float4*)sx0)[tid] = ((const float4*)(x0g + (size_t)b*12))[tid];

    loadX(0);
    bsync();

    for (int iter = 0; iter < 3; ++iter) {
        // x(0) = x0 into row 0 of every alpha's trajectory
        if (tid < 15) {
            const int a = tid / 3, ch = (tid % 3) << 2;
            *(float4*)(staus + a*TAUS_STRIDE + ch) = *(const float4*)(sx0 + ch);
        }
        float ca = 0.f;   // wave0: alphas 0-3 (16-lane groups); wave1 lanes<16: alpha4

        for (int t = 0; t < T_; t += 2) {
            // step t: consume X, prefetch t+1 into Y
            bsync();                                   // B1
            loadY(t+1 < T_ ? t+1 : 0);
            body(Xr0,Xr1,Xr2,Xr3, Xa0,Xa1,Xa2,Xa3, Xs0,Xs1, t,   t*16,    ca);
            // step t+1: consume Y, prefetch t+2 into X (wraps to 0 at iter end)
            bsync();                                   // B1
            loadX(t+2 < T_ ? t+2 : 0);
            body(Yr0,Yr1,Yr2,Yr3, Ya0,Ya1,Ya2,Ya3, Ys0,Ys1, t+1, t*16+16, ca);
        }
        // T_=50 even: X again holds t=0 data for the next iteration

        // ---- reduce costs (16-lane groups), select best alpha ----
        #pragma unroll
        for (int off = 1; off < 16; off <<= 1) ca += __shfl_xor(ca, off, 16);
        if (wave == 0) { if ((lane & 15) == 0) scost[lane >> 4] = ca; }
        else if (lane == 0) scost[4] = ca;
        bsync();
        if (tid == 0) {
            int bi = 0; float bc = scost[0];
            #pragma unroll
            for (int a = 1; a < 5; ++a) {
                if (scost[a] < bc) { bc = scost[a]; bi = a; }  // first-min = jnp.argmin
            }
            sbest = bi;
        }
        bsync();
        const int best = sbest;

        // ---- u_nom <- best trajectory's u; final iter: write taus out ----
        for (int idx = tid; idx < T_*NC_; idx += 128) {
            const int tt = idx >> 2, i = idx & 3;
            sunom[idx] = staus[best*TAUS_STRIDE + tt*16 + 12 + i];
        }
        if (iter == 2) {
            for (int idx = tid; idx < T_*NSC_; idx += 128) {
                const int tt = idx >> 4, j = idx & 15;
                outg[((size_t)tt*B_ + b)*16 + j] = staus[best*TAUS_STRIDE + tt*16 + j];
            }
        }
        bsync();
    } // iter
}

extern "C" void kernel_launch(void* const* d_in, const int* in_sizes, int n_in,
                              void* d_out, int out_size, void* d_ws, size_t ws_size,
                              hipStream_t stream) {
    const float* x0 = (const float*)d_in[0];
    const float* C  = (const float*)d_in[1];
    const float* c  = (const float*)d_in[2];
    const float* F  = (const float*)d_in[3];
    const float* f  = (const float*)d_in[4];
    float* out = (float*)d_out;
    float* Kk  = (float*)d_ws;   // needs 50*2048*52*4 = 21.3 MB

    riccati_kernel<<<B_, 64, 0, stream>>>(C, c, F, f, Kk);
    rollout_kernel<<<B_, 128, 0, stream>>>(x0, C, c, F, f, Kk, out);
}

// Round 7
// 519.972 us; speedup vs baseline: 1.0997x; 1.0974x over previous
//
#include <hip/hip_runtime.h>
#include <math.h>

#define T_   50
#define B_   2048
#define NS_  12
#define NC_  4
#define NSC_ 16
#define LDC  20    // padded LDS row stride for 16-wide matrices (16B-aligned rows, bank-decorrelated)
#define TS   804   // staus per-alpha stride: [a][t][16], 50*16=800 +4 (alpha bank phase 4a%32)

__device__ __forceinline__ float dot4f(const float4 a, const float4 b) {
    return a.x*b.x + a.y*b.y + a.z*b.z + a.w*b.w;
}
__device__ __forceinline__ void axpy4(float4& acc, float s, const float4 v) {
    acc.x += s*v.x; acc.y += s*v.y; acc.z += s*v.z; acc.w += s*v.w;
}
__device__ __forceinline__ float4 ld4(const float* p) { return *(const float4*)p; }

// Wave-local sync. Drains lgkmcnt only; vmcnt stays in flight.
// 0xC07F = vmcnt(63) expcnt(7) lgkmcnt(0).
__device__ __forceinline__ void wsync() {
    __builtin_amdgcn_wave_barrier();
    __builtin_amdgcn_s_waitcnt(0xC07F);
    __builtin_amdgcn_wave_barrier();
}

// Cross-wave barrier: drains LDS (lgkmcnt) but NOT vmcnt, so prefetched
// global loads stay in flight across it. Builtins only (an asm "memory"
// clobber would force a vmcnt(0) drain — the Round-3 regression).
// Verified passing in Rounds 4-6.
__device__ __forceinline__ void bsync() {
    __builtin_amdgcn_wave_barrier();
    __builtin_amdgcn_s_waitcnt(0xC07F);   // lgkmcnt(0) only
    __builtin_amdgcn_s_barrier();
    __builtin_amdgcn_wave_barrier();
}

// ---------------------------------------------------------------------------
// Kernel 1: backward Riccati recursion. One 64-lane wave per batch element.
// (unchanged — isolate the rollout change for attribution)
// ---------------------------------------------------------------------------
struct RicPref { float4 rC, rAux; };

__device__ __forceinline__ RicPref ric_load(
    const float* Cg, const float* cg, const float* Fg, const float* fg,
    int t, int b, int lane)
{
    RicPref p;
    const size_t base = (size_t)t * B_ + b;
    p.rC = ((const float4*)(Cg + base*256))[lane];
    if (lane < 48)      p.rAux = ((const float4*)(Fg + base*192))[lane];
    else if (lane < 52) p.rAux = ((const float4*)(cg + base*16))[lane-48];
    else if (lane < 55) p.rAux = ((const float4*)(fg + base*12))[lane-52];
    return p;
}

__global__ __launch_bounds__(64) void riccati_kernel(
    const float* __restrict__ Cg, const float* __restrict__ cg,
    const float* __restrict__ Fg, const float* __restrict__ fg,
    float* __restrict__ Kk)
{
    const int b    = blockIdx.x;
    const int lane = threadIdx.x;

    __shared__ __align__(16) float sV[144];
    __shared__ __align__(16) float sv[12];
    __shared__ __align__(16) float sF[12*LDC];
    __shared__ __align__(16) float sC[16*LDC];
    __shared__ __align__(16) float sc[16];
    __shared__ __align__(16) float sf[12];
    __shared__ __align__(16) float sP[12*LDC];
    __shared__ __align__(16) float sQ[16*LDC];
    __shared__ __align__(16) float sq[16];
    __shared__ __align__(16) float stmp[12];
    __shared__ __align__(16) float sK[48];
    __shared__ __align__(16) float skk[4];
    __shared__ __align__(16) float sM[144];

    for (int i = lane; i < 144; i += 64) sV[i] = 0.f;
    if (lane < 12) sv[lane] = 0.f;

    RicPref cur = ric_load(Cg, cg, Fg, fg, T_-1, b, lane);
    wsync();

    for (int t = T_ - 1; t >= 0; --t) {
        const size_t base = (size_t)t * B_ + b;

        wsync();
        {
            const int row = lane >> 2, ch = (lane & 3) << 2;
            *(float4*)(sC + row*LDC + ch) = cur.rC;
            if (lane < 48)      *(float4*)(sF + row*LDC + ch) = cur.rAux;
            else if (lane < 52) ((float4*)sc)[lane-48] = cur.rAux;
            else if (lane < 55) ((float4*)sf)[lane-52] = cur.rAux;
        }
        RicPref nxt = ric_load(Cg, cg, Fg, fg, (t > 0) ? t-1 : 0, b, lane);
        wsync();

        if (lane < 48) {
            const int k = lane >> 2, jc = (lane & 3) << 2;
            float4 acc = make_float4(0.f,0.f,0.f,0.f);
            #pragma unroll
            for (int l = 0; l < 12; ++l) {
                axpy4(acc, sV[k*12 + l], *(const float4*)(sF + l*LDC + jc));
            }
            *(float4*)(sP + k*LDC + jc) = acc;
        } else if (lane < 60) {
            const int k = lane - 48;
            float acc = sv[k];
            #pragma unroll
            for (int l = 0; l < 12; ++l) acc += sV[k*12 + l] * sf[l];
            stmp[k] = acc;
        }
        wsync();

        {
            const int i = lane >> 2, jc = (lane & 3) << 2;
            float4 acc = *(const float4*)(sC + i*LDC + jc);
            #pragma unroll
            for (int k = 0; k < 12; ++k) {
                axpy4(acc, sF[k*LDC + i], *(const float4*)(sP + k*LDC + jc));
            }
            *(float4*)(sQ + i*LDC + jc) = acc;
        }
        if (lane < 16) {
            float acc = sc[lane];
            #pragma unroll
            for (int k = 0; k < 12; ++k) acc += sF[k*LDC + lane] * stmp[k];
            sq[lane] = acc;
        }
        wsync();

        {
            const float* Qu = sQ + 12*LDC + 12;
            const float a00=Qu[0],      a01=Qu[1],      a02=Qu[2],      a03=Qu[3];
            const float a11=Qu[LDC+1],  a12=Qu[LDC+2],  a13=Qu[LDC+3];
            const float a22=Qu[2*LDC+2],a23=Qu[2*LDC+3],a33=Qu[3*LDC+3];
            const float l00 = sqrtf(a00), i00 = 1.f/l00;
            const float l10 = a01*i00, l20 = a02*i00, l30 = a03*i00;
            const float l11 = sqrtf(a11 - l10*l10), i11 = 1.f/l11;
            const float l21 = (a12 - l20*l10)*i11;
            const float l31 = (a13 - l30*l10)*i11;
            const float l22 = sqrtf(a22 - l20*l20 - l21*l21), i22 = 1.f/l22;
            const float l32 = (a23 - l30*l20 - l31*l21)*i22;
            const float l33 = sqrtf(a33 - l30*l30 - l31*l31 - l32*l32), i33 = 1.f/l33;
            if (lane < 13) {
                float r0, r1, r2, r3;
                if (lane < 12) {
                    r0 = sQ[12*LDC + lane]; r1 = sQ[13*LDC + lane];
                    r2 = sQ[14*LDC + lane]; r3 = sQ[15*LDC + lane];
                } else {
                    r0 = sq[12]; r1 = sq[13]; r2 = sq[14]; r3 = sq[15];
                }
                const float y0 = r0*i00;
                const float y1 = (r1 - l10*y0)*i11;
                const float y2 = (r2 - l20*y0 - l21*y1)*i22;
                const float y3 = (r3 - l30*y0 - l31*y1 - l32*y2)*i33;
                const float z3 = y3*i33;
                const float z2 = (y2 - l32*z3)*i22;
                const float z1 = (y1 - l21*z2 - l31*z3)*i11;
                const float z0 = (y0 - l10*z1 - l20*z2 - l30*z3)*i00;
                if (lane < 12) {
                    sK[0*12+lane] = -z0; sK[1*12+lane] = -z1;
                    sK[2*12+lane] = -z2; sK[3*12+lane] = -z3;
                } else {
                    skk[0] = -z0; skk[1] = -z1; skk[2] = -z2; skk[3] = -z3;
                }
            }
        }
        wsync();

        if (lane < 52) {
            (Kk + base*52)[lane] = (lane < 48) ? sK[lane] : skk[lane-48];
        }
        if (lane < 36) {
            const int i = lane / 3, jc = (lane % 3) << 2;
            float4 acc = make_float4(0.f,0.f,0.f,0.f);
            #pragma unroll
            for (int m = 0; m < 4; ++m) {
                axpy4(acc, sK[m*12 + i], *(const float4*)(sQ + (12+m)*LDC + jc));
            }
            *(float4*)(sM + i*12 + jc) = acc;
        } else if (lane < 48) {
            const int i = lane - 36;
            float acc = sq[i];
            #pragma unroll
            for (int m = 0; m < 4; ++m) acc += sQ[i*LDC + 12 + m] * skk[m];
            sv[i] = acc;
        }
        wsync();

        if (lane < 36) {
            const int i = lane / 3, jc = (lane % 3) << 2;
            const float4 q  = *(const float4*)(sQ + i*LDC + jc);
            const float4 m1 = *(const float4*)(sM + i*12 + jc);
            const float t0 = sM[(jc+0)*12 + i];
            const float t1 = sM[(jc+1)*12 + i];
            const float t2 = sM[(jc+2)*12 + i];
            const float t3 = sM[(jc+3)*12 + i];
            float4 r;
            r.x = q.x + 0.5f*(m1.x + t0);
            r.y = q.y + 0.5f*(m1.y + t1);
            r.z = q.z + 0.5f*(m1.z + t2);
            r.w = q.w + 0.5f*(m1.w + t3);
            *(float4*)(sV + i*12 + jc) = r;
        }
        cur = nxt;
    }
}

// ---------------------------------------------------------------------------
// Kernel 2: rollout v7 — ONE barrier per step.
//  - LDS double-buffered staging: wave0 stages tile(t+1) into the idle parity
//    buffer during step t (no publish barrier needed; the single loop-top
//    bsync publishes it together with x(t+1)).
//  - u(t) off the barrier path: lanes 0-19 of EACH wave run the identical
//    masked u-computation (bit-identical across waves), then 4 in-wave
//    __shfl broadcasts give every lane its alpha's u in REGISTERS.
//    tau's u-chunk comes from registers; no LDS round trip, no second barrier.
//  - wave0 lanes 0-19 write u(t) to staus (only read at iter end).
//  - within-step LDS accesses pairwise disjoint: x(t) reads [t][0..11],
//    x(t+1) writes [t+1][0..11], u(t) writes [t][12..15].
// ---------------------------------------------------------------------------
struct RollAux { float4 r1, r2; };

__device__ __forceinline__ RollAux aux_load(
    const float* cg, const float* Fg, const float* fg, const float* Kk,
    int t, int b, int lane)
{
    RollAux p;
    const size_t base = (size_t)t * B_ + b;
    if (lane < 48)      p.r1 = ((const float4*)(Fg + base*192))[lane];
    else if (lane < 61) p.r1 = ((const float4*)(Kk + base*52))[lane-48];
    else                p.r1 = ((const float4*)(cg + base*16))[lane-61];
    if (lane == 0)      p.r2 = ((const float4*)(cg + base*16))[3];
    else if (lane < 4)  p.r2 = ((const float4*)(fg + base*12))[lane-1];
    return p;
}

__global__ __launch_bounds__(128) void rollout_kernel(
    const float* __restrict__ x0g, const float* __restrict__ Cg,
    const float* __restrict__ cg,  const float* __restrict__ Fg,
    const float* __restrict__ fg,  const float* __restrict__ Kk,
    float* __restrict__ outg)
{
    const int b    = blockIdx.x;
    const int tid  = threadIdx.x;
    const int wave = tid >> 6;
    const int lane = tid & 63;

    __shared__ __align__(16) float staus[5*TS];   // [a][t][16]
    __shared__ __align__(16) float sunom[T_*NC_];
    __shared__ __align__(16) float sx0[12];
    __shared__ __align__(16) float bC[2][16*LDC]; // staged C, double-buffered
    __shared__ __align__(16) float bF[2][12*LDC];
    __shared__ __align__(16) float bK[2][56];     // K 4x12 + kk[4]
    __shared__ __align__(16) float bcv[2][16];
    __shared__ __align__(16) float bfv[2][12];
    __shared__ float scost[5];
    __shared__ int   sbest;

    // ---- task mapping (as v4): 0..79 cost (a=task>>4,i=task&15);
    //      80..127 x_next (v=task-80, a=v/12, i=v%12) ----
    const int  task    = wave*64 + lane;
    const bool is_cost = task < 80;
    int a1, i1;
    if (is_cost) { a1 = task >> 4; i1 = task & 15; }
    else { const int v = task - 80; a1 = v / 12; i1 = v - a1*12; }
    float* taub1 = staus + a1*TS;
    float* taub4 = staus + 4*TS;

    // per-parity row/addend pointers (static buffer selection via 2x unroll)
    const float* rowE = (is_cost ? bC[0] : bF[0]) + i1*LDC;
    const float* rowO = (is_cost ? bC[1] : bF[1]) + i1*LDC;
    const float* addE = (is_cost ? bcv[0] : bfv[0]) + i1;
    const float* addO = (is_cost ? bcv[1] : bfv[1]) + i1;

    // u-computation constants (lanes 0..19 of BOTH waves: a=lane>>2, j=lane&3)
    const int   aU  = lane >> 2, jU = lane & 3;
    const float alU = ldexpf(1.0f, -aU);   // 0.5^a

    // wave0 prefetch registers (C + aux); wave1 never stages
    float4  rC;
    RollAux rA;

    auto stage = [&](float* bCn, float* bFn, float* bKn, float* bcn, float* bfn,
                     int tn_next) {
        // write staged tile from prefetch regs, then issue loads for tn_next
        const int row = lane >> 2, ch = (lane & 3) << 2;
        *(float4*)(bCn + row*LDC + ch) = rC;
        if (lane < 48)      *(float4*)(bFn + row*LDC + ch) = rA.r1;
        else if (lane < 61) ((float4*)bKn)[lane-48] = rA.r1;
        else                ((float4*)bcn)[lane-61] = rA.r1;
        if (lane == 0)      ((float4*)bcn)[3] = rA.r2;
        else if (lane < 4)  ((float4*)bfn)[lane-1] = rA.r2;
        rC = ((const float4*)(Cg + ((size_t)tn_next * B_ + b)*256))[lane];
        rA = aux_load(cg, Fg, fg, Kk, tn_next, b, lane);
    };

    // one rollout step on staged parity-p buffers; stages tile(t+1) into ^p.
    auto step = [&](int t,
                    const float* bKp, const float* bfp,
                    float* bCn, float* bFn, float* bKn, float* bcn, float* bfn,
                    const float* row1, const float* add1, float& ca) {
        const int toff = t*16;

        // ---- u(t): lanes<20 of each wave, identical code -> identical bits ----
        float uval = 0.f;
        if (lane < 20) {
            const float* Kr = bKp + jU*12;
            const float* xU = staus + aU*TS + toff;
            float ulqr = dot4f(ld4(Kr  ), ld4(xU  ))
                       + dot4f(ld4(Kr+4), ld4(xU+4))
                       + dot4f(ld4(Kr+8), ld4(xU+8))
                       + bKp[48 + jU];
            float u = (1.f - alU)*sunom[t*4 + jU] + alU*ulqr;
            uval = fminf(1.f, fmaxf(-1.f, u));
            if (wave == 0) staus[aU*TS + toff + 12 + jU] = uval;  // for iter-end only
        }
        float4 ul;   // u(t) of this lane's alpha, in registers
        ul.x = __shfl(uval, a1*4 + 0, 64);
        ul.y = __shfl(uval, a1*4 + 1, 64);
        ul.z = __shfl(uval, a1*4 + 2, 64);
        ul.w = __shfl(uval, a1*4 + 3, 64);

        // ---- unified cost / x_next body ----
        const float* xp = taub1 + toff;
        const float4 x0 = ld4(xp), x1 = ld4(xp+4), x2 = ld4(xp+8);
        const float  av = add1[0];
        float acc = is_cost ? 0.f : av;        // x_next starts at f_i (order-exact)
        acc += dot4f(ld4(row1   ), x0);
        acc += dot4f(ld4(row1+ 4), x1);
        acc += dot4f(ld4(row1+ 8), x2);
        acc += dot4f(ld4(row1+12), ul);
        const bool tnl = (t != T_-1);
        if (is_cost) {
            float taui;
            if (i1 < 12) taui = xp[i1];
            else taui = (i1 == 12) ? ul.x : (i1 == 13) ? ul.y
                      : (i1 == 14) ? ul.z : ul.w;
            ca += (0.5f*acc + av) * taui;
        } else if (tnl) {
            taub1[toff + 16 + i1] = acc;       // x(t+1)
        }

        // ---- tail: x_next alpha4 (wave1 lanes<12; their a1==4 so x0..x2, ul reuse) ----
        if (wave == 1 && lane < 12 && tnl) {
            const float* Fr = (bCn == bC[1] ? bF[0] : bF[1]) + lane*LDC; // current parity F
            float acc4 = bfp[lane];
            acc4 += dot4f(ld4(Fr   ), x0);
            acc4 += dot4f(ld4(Fr+ 4), x1);
            acc4 += dot4f(ld4(Fr+ 8), x2);
            acc4 += dot4f(ld4(Fr+12), ul);
            taub4[toff + 16 + lane] = acc4;
        }

        // ---- wave0: stage tile(t+1) into idle parity; prefetch tile(t+2) ----
        if (wave == 0) {
            int tn = t + 2; if (tn >= T_) tn -= T_;
            stage(bCn, bFn, bKn, bcn, bfn, tn);
        }
    };

    // ---------------- prologue ----------------
    for (int i = tid; i < T_*NC_; i += 128) sunom[i] = 0.f;
    if (tid < 3) ((float4*)sx0)[tid] = ((const float4*)(x0g + (size_t)b*12))[tid];

    if (wave == 0) {
        rC = ((const float4*)(Cg + (size_t)b*256))[lane];   // tile 0
        rA = aux_load(cg, Fg, fg, Kk, 0, b, lane);
        stage(bC[0], bF[0], bK[0], bcv[0], bfv[0], 1);      // staged[0]=t0; regs<-t1
    }
    bsync();

    for (int iter = 0; iter < 3; ++iter) {
        // x(0) = x0 into row t=0 of every alpha
        if (tid < 15) {
            const int a = tid / 3, ch = (tid % 3) << 2;
            *(float4*)(staus + a*TS + ch) = *(const float4*)(sx0 + ch);
        }
        float ca = 0.f;   // wave0: alphas 0-3 (16-lane groups); wave1 lanes<16: alpha4

        for (int t = 0; t < T_; t += 2) {
            bsync();   // publishes staged[t&1], x(t), u(t-1)
            step(t,   bK[0], bfv[0],
                 bC[1], bF[1], bK[1], bcv[1], bfv[1], rowE, addE, ca);
            bsync();
            step(t+1, bK[1], bfv[1],
                 bC[0], bF[0], bK[0], bcv[0], bfv[0], rowO, addO, ca);
        }
        // after t=49 (p=1): staged[0] = tile(0), prefetch regs hold tile(1) — next iter ready

        // ---- reduce costs (16-lane groups), select best alpha ----
        #pragma unroll
        for (int off = 1; off < 16; off <<= 1) ca += __shfl_xor(ca, off, 16);
        if (wave == 0) { if ((lane & 15) == 0) scost[lane >> 4] = ca; }
        else if (lane == 0) scost[4] = ca;
        bsync();   // drains last step's staus writes too
        if (tid == 0) {
            int bi = 0; float bc = scost[0];
            #pragma unroll
            for (int a = 1; a < 5; ++a) {
                if (scost[a] < bc) { bc = scost[a]; bi = a; }  // first-min = jnp.argmin
            }
            sbest = bi;
        }
        bsync();
        const int best = sbest;

        // ---- u_nom <- best trajectory's u; final iter: write taus out ----
        for (int idx = tid; idx < T_*NC_; idx += 128) {
            const int tt = idx >> 2, i = idx & 3;
            sunom[idx] = staus[best*TS + tt*16 + 12 + i];
        }
        if (iter == 2) {
            for (int idx = tid; idx < T_*NSC_; idx += 128) {
                const int tt = idx >> 4, j = idx & 15;
                outg[((size_t)tt*B_ + b)*16 + j] = staus[best*TS + tt*16 + j];
            }
        }
        bsync();   // WAR before next iter's x(0) writes / staged reuse
    } // iter
}

extern "C" void kernel_launch(void* const* d_in, const int* in_sizes, int n_in,
                              void* d_out, int out_size, void* d_ws, size_t ws_size,
                              hipStream_t stream) {
    const float* x0 = (const float*)d_in[0];
    const float* C  = (const float*)d_in[1];
    const float* c  = (const float*)d_in[2];
    const float* F  = (const float*)d_in[3];
    const float* f  = (const float*)d_in[4];
    float* out = (float*)d_out;
    float* Kk  = (float*)d_ws;   // needs 50*2048*52*4 = 21.3 MB

    riccati_kernel<<<B_, 64, 0, stream>>>(C, c, F, f, Kk);
    rollout_kernel<<<B_, 128, 0, stream>>>(x0, C, c, F, f, Kk, out);
}

// Round 8
// 474.776 us; speedup vs baseline: 1.2044x; 1.0952x over previous
//
#include <hip/hip_runtime.h>
#include <math.h>

#define T_   50
#define B_   2048
#define NS_  12
#define NC_  4
#define NSC_ 16
#define LDC  20          // padded LDS row stride for 16-wide matrices (bank decorrelation)
#define TAUS_STRIDE 808  // per-alpha stride for tau trajectories (50*16=800, +8 pad)

__device__ __forceinline__ float dot4f(const float4 a, const float4 b) {
    return a.x*b.x + a.y*b.y + a.z*b.z + a.w*b.w;
}
__device__ __forceinline__ void axpy4(float4& acc, float s, const float4 v) {
    acc.x += s*v.x; acc.y += s*v.y; acc.z += s*v.z; acc.w += s*v.w;
}
__device__ __forceinline__ float4 ld4(const float* p) { return *(const float4*)p; }

// Wave-local sync. Drains lgkmcnt only; vmcnt stays in flight.
// 0xC07F = vmcnt(63) expcnt(7) lgkmcnt(0).
__device__ __forceinline__ void wsync() {
    __builtin_amdgcn_wave_barrier();
    __builtin_amdgcn_s_waitcnt(0xC07F);
    __builtin_amdgcn_wave_barrier();
}

// Cross-wave barrier: drains LDS (lgkmcnt) but NOT vmcnt. Builtins only
// (asm "memory" clobber would force a vmcnt(0) drain — Round-3 regression).
// Verified passing in Rounds 4-7.
__device__ __forceinline__ void bsync() {
    __builtin_amdgcn_wave_barrier();
    __builtin_amdgcn_s_waitcnt(0xC07F);   // lgkmcnt(0) only
    __builtin_amdgcn_s_barrier();
    __builtin_amdgcn_wave_barrier();
}

// ---------------------------------------------------------------------------
// Kernel 1: backward Riccati recursion — v8: LDS-instruction-count cut.
// Audit showed ~149 LDS wave-instructions/step (scalar sV reads, scalar F
// columns, scalar K columns) saturating the LDS issue pipe. This version:
//   - V rows read as 3x ds_read_b128 (was 12x b32) in P and tmp phases
//   - F^T staged once (+4 b32 writes), F-column reads become 3x b128 (x2 uses)
//   - Quu read as 4x b128 (was 10x b32)
//   - K stored transposed KT[12][4]: chol writes 1x b128/lane (was 4x b32),
//     M-phase reads 1x b128 (was 4x b32); skk/Qxu-row/stmp/sf vectorized
// FLOP sequence per output value is unchanged (same l/k/m order) -> results
// bit-identical to the verified kernel.
// ---------------------------------------------------------------------------
struct RicPref { float4 rC, rAux; };

__device__ __forceinline__ RicPref ric_load(
    const float* Cg, const float* cg, const float* Fg, const float* fg,
    int t, int b, int lane)
{
    RicPref p;
    const size_t base = (size_t)t * B_ + b;
    p.rC = ((const float4*)(Cg + base*256))[lane];
    if (lane < 48)      p.rAux = ((const float4*)(Fg + base*192))[lane];
    else if (lane < 52) p.rAux = ((const float4*)(cg + base*16))[lane-48];
    else if (lane < 55) p.rAux = ((const float4*)(fg + base*12))[lane-52];
    return p;
}

__global__ __launch_bounds__(64) void riccati_kernel(
    const float* __restrict__ Cg, const float* __restrict__ cg,
    const float* __restrict__ Fg, const float* __restrict__ fg,
    float* __restrict__ Kk)
{
    const int b    = blockIdx.x;
    const int lane = threadIdx.x;

    __shared__ __align__(16) float sV[144];      // V   12x12 (stride 12)
    __shared__ __align__(16) float sv[12];
    __shared__ __align__(16) float sF[12*LDC];   // F   12x16 (stride 20)
    __shared__ __align__(16) float sFT[16*12];   // F^T 16x12 (stride 12) — NEW
    __shared__ __align__(16) float sC[16*LDC];   // C   16x16 (stride 20)
    __shared__ __align__(16) float sc[16];
    __shared__ __align__(16) float sf[12];
    __shared__ __align__(16) float sP[12*LDC];   // P = V*F  12x16
    __shared__ __align__(16) float sQ[16*LDC];   // Q 16x16
    __shared__ __align__(16) float sq[16];
    __shared__ __align__(16) float stmp[12];     // V f + v
    __shared__ __align__(16) float sKT[48];      // K^T 12x4 (KT[i][m] = K[m][i])
    __shared__ __align__(16) float skk[4];
    __shared__ __align__(16) float sM[144];      // M = K^T Qux  12x12 (stride 12)

    for (int i = lane; i < 144; i += 64) sV[i] = 0.f;
    if (lane < 12) sv[lane] = 0.f;

    RicPref cur = ric_load(Cg, cg, Fg, fg, T_-1, b, lane);
    wsync();

    for (int t = T_ - 1; t >= 0; --t) {
        const size_t base = (size_t)t * B_ + b;

        // ---- stage current step's data (incl. F^T) from prefetch registers ----
        wsync();   // WAR: prior phases' LDS reads complete before overwrite
        {
            const int row = lane >> 2, ch = (lane & 3) << 2;
            *(float4*)(sC + row*LDC + ch) = cur.rC;
            if (lane < 48) {
                *(float4*)(sF + row*LDC + ch) = cur.rAux;
                sFT[(ch+0)*12 + row] = cur.rAux.x;
                sFT[(ch+1)*12 + row] = cur.rAux.y;
                sFT[(ch+2)*12 + row] = cur.rAux.z;
                sFT[(ch+3)*12 + row] = cur.rAux.w;
            }
            else if (lane < 52) ((float4*)sc)[lane-48] = cur.rAux;
            else if (lane < 55) ((float4*)sf)[lane-52] = cur.rAux;
        }
        RicPref nxt = ric_load(Cg, cg, Fg, fg, (t > 0) ? t-1 : 0, b, lane);
        wsync();

        // ---- P = V * F (12x16); tmp = V f + v ----
        if (lane < 48) {
            const int k = lane >> 2, jc = (lane & 3) << 2;
            const float4 v0 = ld4(sV + k*12), v1 = ld4(sV + k*12 + 4),
                         v2 = ld4(sV + k*12 + 8);
            float4 acc = make_float4(0.f,0.f,0.f,0.f);
            axpy4(acc, v0.x, ld4(sF + 0*LDC + jc));
            axpy4(acc, v0.y, ld4(sF + 1*LDC + jc));
            axpy4(acc, v0.z, ld4(sF + 2*LDC + jc));
            axpy4(acc, v0.w, ld4(sF + 3*LDC + jc));
            axpy4(acc, v1.x, ld4(sF + 4*LDC + jc));
            axpy4(acc, v1.y, ld4(sF + 5*LDC + jc));
            axpy4(acc, v1.z, ld4(sF + 6*LDC + jc));
            axpy4(acc, v1.w, ld4(sF + 7*LDC + jc));
            axpy4(acc, v2.x, ld4(sF + 8*LDC + jc));
            axpy4(acc, v2.y, ld4(sF + 9*LDC + jc));
            axpy4(acc, v2.z, ld4(sF + 10*LDC + jc));
            axpy4(acc, v2.w, ld4(sF + 11*LDC + jc));
            *(float4*)(sP + k*LDC + jc) = acc;
        } else if (lane < 60) {
            const int k = lane - 48;
            const float4 v0 = ld4(sV + k*12), v1 = ld4(sV + k*12 + 4),
                         v2 = ld4(sV + k*12 + 8);
            const float4 f0 = ld4(sf), f1 = ld4(sf + 4), f2 = ld4(sf + 8);
            float acc = sv[k];
            acc += v0.x*f0.x; acc += v0.y*f0.y; acc += v0.z*f0.z; acc += v0.w*f0.w;
            acc += v1.x*f1.x; acc += v1.y*f1.y; acc += v1.z*f1.z; acc += v1.w*f1.w;
            acc += v2.x*f2.x; acc += v2.y*f2.y; acc += v2.z*f2.z; acc += v2.w*f2.w;
            stmp[k] = acc;
        }
        wsync();

        // ---- Q = C + F^T P (16x16); q = c + F^T tmp ----
        {
            const int i = lane >> 2, jc = (lane & 3) << 2;
            const float4 g0 = ld4(sFT + i*12), g1 = ld4(sFT + i*12 + 4),
                         g2 = ld4(sFT + i*12 + 8);   // F[k][i], k=0..11
            float4 acc = ld4(sC + i*LDC + jc);
            axpy4(acc, g0.x, ld4(sP + 0*LDC + jc));
            axpy4(acc, g0.y, ld4(sP + 1*LDC + jc));
            axpy4(acc, g0.z, ld4(sP + 2*LDC + jc));
            axpy4(acc, g0.w, ld4(sP + 3*LDC + jc));
            axpy4(acc, g1.x, ld4(sP + 4*LDC + jc));
            axpy4(acc, g1.y, ld4(sP + 5*LDC + jc));
            axpy4(acc, g1.z, ld4(sP + 6*LDC + jc));
            axpy4(acc, g1.w, ld4(sP + 7*LDC + jc));
            axpy4(acc, g2.x, ld4(sP + 8*LDC + jc));
            axpy4(acc, g2.y, ld4(sP + 9*LDC + jc));
            axpy4(acc, g2.z, ld4(sP + 10*LDC + jc));
            axpy4(acc, g2.w, ld4(sP + 11*LDC + jc));
            *(float4*)(sQ + i*LDC + jc) = acc;
        }
        if (lane < 16) {
            const float4 g0 = ld4(sFT + lane*12), g1 = ld4(sFT + lane*12 + 4),
                         g2 = ld4(sFT + lane*12 + 8);
            const float4 t0 = ld4(stmp), t1 = ld4(stmp + 4), t2 = ld4(stmp + 8);
            float acc = sc[lane];
            acc += g0.x*t0.x; acc += g0.y*t0.y; acc += g0.z*t0.z; acc += g0.w*t0.w;
            acc += g1.x*t1.x; acc += g1.y*t1.y; acc += g1.z*t1.z; acc += g1.w*t1.w;
            acc += g2.x*t2.x; acc += g2.y*t2.y; acc += g2.z*t2.z; acc += g2.w*t2.w;
            sq[lane] = acc;
        }
        wsync();

        // ---- solve Quu * sol = [Qux | qu] via redundant 4x4 Cholesky ----
        {
            const float4 qu0 = ld4(sQ + 12*LDC + 12);
            const float4 qu1 = ld4(sQ + 13*LDC + 12);
            const float4 qu2 = ld4(sQ + 14*LDC + 12);
            const float4 qu3 = ld4(sQ + 15*LDC + 12);
            const float a00=qu0.x, a01=qu0.y, a02=qu0.z, a03=qu0.w;
            const float a11=qu1.y, a12=qu1.z, a13=qu1.w;
            const float a22=qu2.z, a23=qu2.w, a33=qu3.w;
            const float l00 = sqrtf(a00), i00 = 1.f/l00;
            const float l10 = a01*i00, l20 = a02*i00, l30 = a03*i00;
            const float l11 = sqrtf(a11 - l10*l10), i11 = 1.f/l11;
            const float l21 = (a12 - l20*l10)*i11;
            const float l31 = (a13 - l30*l10)*i11;
            const float l22 = sqrtf(a22 - l20*l20 - l21*l21), i22 = 1.f/l22;
            const float l32 = (a23 - l30*l20 - l31*l21)*i22;
            const float l33 = sqrtf(a33 - l30*l30 - l31*l31 - l32*l32), i33 = 1.f/l33;
            if (lane < 13) {   // one RHS column per lane
                float r0, r1, r2, r3;
                if (lane < 12) {
                    r0 = sQ[12*LDC + lane]; r1 = sQ[13*LDC + lane];
                    r2 = sQ[14*LDC + lane]; r3 = sQ[15*LDC + lane];
                } else {
                    r0 = sq[12]; r1 = sq[13]; r2 = sq[14]; r3 = sq[15];
                }
                const float y0 = r0*i00;
                const float y1 = (r1 - l10*y0)*i11;
                const float y2 = (r2 - l20*y0 - l21*y1)*i22;
                const float y3 = (r3 - l30*y0 - l31*y1 - l32*y2)*i33;
                const float z3 = y3*i33;
                const float z2 = (y2 - l32*z3)*i22;
                const float z1 = (y1 - l21*z2 - l31*z3)*i11;
                const float z0 = (y0 - l10*z1 - l20*z2 - l30*z3)*i00;
                if (lane < 12) {
                    *(float4*)(sKT + lane*4) = make_float4(-z0,-z1,-z2,-z3);
                } else {
                    *(float4*)skk = make_float4(-z0,-z1,-z2,-z3);
                }
            }
        }
        wsync();

        // ---- emit K,kk; M = K^T Qux; v' = qx + Qxu kk ----
        if (lane < 52) {
            const float kv = (lane < 48) ? sKT[(lane % 12)*4 + (lane / 12)]
                                         : skk[lane-48];
            (Kk + base*52)[lane] = kv;
        }
        if (lane < 36) {
            const int i = lane / 3, jc = (lane % 3) << 2;
            const float4 kt = ld4(sKT + i*4);   // K[m][i], m=0..3
            float4 acc = make_float4(0.f,0.f,0.f,0.f);
            axpy4(acc, kt.x, ld4(sQ + 12*LDC + jc));
            axpy4(acc, kt.y, ld4(sQ + 13*LDC + jc));
            axpy4(acc, kt.z, ld4(sQ + 14*LDC + jc));
            axpy4(acc, kt.w, ld4(sQ + 15*LDC + jc));
            *(float4*)(sM + i*12 + jc) = acc;
        } else if (lane < 48) {
            const int i = lane - 36;
            const float4 qx = ld4(sQ + i*LDC + 12);   // Qxu row i (cols 12..15)
            const float4 k4 = ld4(skk);
            float acc = sq[i];
            acc += qx.x*k4.x; acc += qx.y*k4.y; acc += qx.z*k4.z; acc += qx.w*k4.w;
            sv[i] = acc;   // v' (no readers of sv until next t's phase 1)
        }
        wsync();

        // ---- V' = Qxx + 0.5(M + M^T)  (matches reference symmetrization) ----
        if (lane < 36) {
            const int i = lane / 3, jc = (lane % 3) << 2;
            const float4 q  = ld4(sQ + i*LDC + jc);
            const float4 m1 = ld4(sM + i*12 + jc);
            const float t0 = sM[(jc+0)*12 + i];
            const float t1 = sM[(jc+1)*12 + i];
            const float t2 = sM[(jc+2)*12 + i];
            const float t3 = sM[(jc+3)*12 + i];
            float4 r;
            r.x = q.x + 0.5f*(m1.x + t0);
            r.y = q.y + 0.5f*(m1.y + t1);
            r.z = q.z + 0.5f*(m1.z + t2);
            r.w = q.w + 0.5f*(m1.w + t3);
            *(float4*)(sV + i*12 + jc) = r;
        }
        cur = nxt;
        // loop-top wsync orders V' writes vs next step's P reads
    }
}

// ---------------------------------------------------------------------------
// Kernel 2: rollout — v4 VERBATIM (verified 180 µs, Round 4).
// Two waves/block; x_next written into staus; 2 non-draining bsync per step.
// ---------------------------------------------------------------------------
struct RollAux { float4 r1, r2; };

__device__ __forceinline__ RollAux aux_load(
    const float* cg, const float* Fg, const float* fg, const float* Kk,
    int t, int b, int lane)
{
    RollAux p;
    const size_t base = (size_t)t * B_ + b;
    if (lane < 48)      p.r1 = ((const float4*)(Fg + base*192))[lane];
    else if (lane < 61) p.r1 = ((const float4*)(Kk + base*52))[lane-48];
    else                p.r1 = ((const float4*)(cg + base*16))[lane-61];
    if (lane == 0)      p.r2 = ((const float4*)(cg + base*16))[3];
    else if (lane < 4)  p.r2 = ((const float4*)(fg + base*12))[lane-1];
    return p;
}

__global__ __launch_bounds__(128, 4) void rollout_kernel(
    const float* __restrict__ x0g, const float* __restrict__ Cg,
    const float* __restrict__ cg,  const float* __restrict__ Fg,
    const float* __restrict__ fg,  const float* __restrict__ Kk,
    float* __restrict__ outg)
{
    const int b    = blockIdx.x;
    const int tid  = threadIdx.x;
    const int wave = tid >> 6;
    const int lane = tid & 63;

    __shared__ __align__(16) float staus[5*TAUS_STRIDE]; // [a][t][16]
    __shared__ __align__(16) float sunom[T_*NC_];        // [t][4]
    __shared__ __align__(16) float sx0[12];
    __shared__ __align__(16) float sC[16*LDC];
    __shared__ __align__(16) float sF[12*LDC];
    __shared__ __align__(16) float sKk[56];
    __shared__ __align__(16) float sc[16];
    __shared__ __align__(16) float sf[12];
    __shared__ float scost[5];
    __shared__ int   sbest;

    const int  task    = wave*64 + lane;
    const bool is_cost = task < 80;
    int a1, i1;
    if (is_cost) { a1 = task >> 4; i1 = task & 15; }
    else { const int v = task - 80; a1 = v / 12; i1 = v - a1*12; }
    const float* row1  = (is_cost ? (const float*)sC : (const float*)sF) + i1*LDC;
    const float* add1  = (is_cost ? (const float*)sc : (const float*)sf) + i1;
    float*       taub1 = staus + a1*TAUS_STRIDE;

    const int    iT    = (lane < 12) ? lane : 0;
    const float* rowT  = sF + iT*LDC;
    float*       taubT = staus + 4*TAUS_STRIDE;

    const int    aA  = (lane < 20) ? (lane >> 2) : 0;
    const int    iA  = lane & 3;
    const float  alA = ldexpf(1.0f, -aA);     // 0.5^a
    const float* KrA = sKk + iA*12;
    float*       tauA = staus + aA*TAUS_STRIDE;

    for (int i = tid; i < T_*NC_; i += 128) sunom[i] = 0.f;
    if (tid < 3) ((float4*)sx0)[tid] = ((const float4*)(x0g + (size_t)b*12))[tid];

    float4  curC;
    RollAux curA;
    if (wave == 0) curC = ((const float4*)(Cg + (size_t)b*256))[lane];
    else           curA = aux_load(cg, Fg, fg, Kk, 0, b, lane);
    bsync();

    for (int iter = 0; iter < 3; ++iter) {
        if (tid < 15) {
            const int a = tid / 3, ch = (tid % 3) << 2;
            *(float4*)(staus + a*TAUS_STRIDE + ch) = *(const float4*)(sx0 + ch);
        }
        float ca = 0.f;
        int toff = 0;

        for (int t = 0; t < T_; ++t) {
            bsync();   // B1: WAR on staged arrays; publishes x(t)
            if (wave == 0) {
                const int row = lane >> 2, ch = (lane & 3) << 2;
                *(float4*)(sC + row*LDC + ch) = curC;
                curC = ((const float4*)(Cg +
                          ((size_t)((t+1 < T_) ? t+1 : 0) * B_ + b)*256))[lane];
            } else {
                {
                    const int row = lane >> 2, ch = (lane & 3) << 2;
                    if (lane < 48)      *(float4*)(sF + row*LDC + ch) = curA.r1;
                    else if (lane < 61) ((float4*)sKk)[lane-48] = curA.r1;
                    else                ((float4*)sc)[lane-61]  = curA.r1;
                    if (lane == 0)      ((float4*)sc)[3] = curA.r2;
                    else if (lane < 4)  ((float4*)sf)[lane-1] = curA.r2;
                }
                curA = aux_load(cg, Fg, fg, Kk, (t+1 < T_) ? t+1 : 0, b, lane);
                wsync();
                if (lane < 20) {
                    const float* x = tauA + toff;
                    float ulqr = dot4f(*(const float4*)(KrA+0), *(const float4*)(x+0))
                               + dot4f(*(const float4*)(KrA+4), *(const float4*)(x+4))
                               + dot4f(*(const float4*)(KrA+8), *(const float4*)(x+8))
                               + sKk[48 + iA];
                    float u = (1.f - alA)*sunom[t*4 + iA] + alA*ulqr;
                    u = fminf(1.f, fmaxf(-1.f, u));
                    tauA[toff + 12 + iA] = u;
                }
            }
            bsync();   // B2: staged data and u(t) visible

            const bool tnl = (t != T_-1);
            {
                const float* tau = taub1 + toff;
                const float  av  = add1[0];
                float acc = is_cost ? 0.f : av;
                acc += dot4f(*(const float4*)(row1+ 0), *(const float4*)(tau+ 0));
                acc += dot4f(*(const float4*)(row1+ 4), *(const float4*)(tau+ 4));
                acc += dot4f(*(const float4*)(row1+ 8), *(const float4*)(tau+ 8));
                acc += dot4f(*(const float4*)(row1+12), *(const float4*)(tau+12));
                if (is_cost)  ca += (0.5f*acc + av) * tau[i1];
                else if (tnl) taub1[toff + 16 + i1] = acc;
            }
            if (wave == 0 && lane < 12 && tnl) {
                const float* tau = taubT + toff;
                float acc = sf[iT];
                acc += dot4f(*(const float4*)(rowT+ 0), *(const float4*)(tau+ 0));
                acc += dot4f(*(const float4*)(rowT+ 4), *(const float4*)(tau+ 4));
                acc += dot4f(*(const float4*)(rowT+ 8), *(const float4*)(tau+ 8));
                acc += dot4f(*(const float4*)(rowT+12), *(const float4*)(tau+12));
                taubT[toff + 16 + iT] = acc;
            }
            toff += 16;
        } // t

        #pragma unroll
        for (int off = 1; off < 16; off <<= 1) ca += __shfl_xor(ca, off, 16);
        if (wave == 0) { if ((lane & 15) == 0) scost[lane >> 4] = ca; }
        else if (lane == 0) scost[4] = ca;
        bsync();
        if (tid == 0) {
            int bi = 0; float bc = scost[0];
            #pragma unroll
            for (int a = 1; a < 5; ++a) {
                if (scost[a] < bc) { bc = scost[a]; bi = a; }  // first-min = jnp.argmin
            }
            sbest = bi;
        }
        bsync();
        const int best = sbest;

        for (int idx = tid; idx < T_*NC_; idx += 128) {
            const int tt = idx >> 2, i = idx & 3;
            sunom[idx] = staus[best*TAUS_STRIDE + tt*16 + 12 + i];
        }
        if (iter == 2) {
            for (int idx = tid; idx < T_*NSC_; idx += 128) {
                const int tt = idx >> 4, j = idx & 15;
                outg[((size_t)tt*B_ + b)*16 + j] = staus[best*TAUS_STRIDE + tt*16 + j];
            }
        }
        bsync();
    } // iter
}

extern "C" void kernel_launch(void* const* d_in, const int* in_sizes, int n_in,
                              void* d_out, int out_size, void* d_ws, size_t ws_size,
                              hipStream_t stream) {
    const float* x0 = (const float*)d_in[0];
    const float* C  = (const float*)d_in[1];
    const float* c  = (const float*)d_in[2];
    const float* F  = (const float*)d_in[3];
    const float* f  = (const float*)d_in[4];
    float* out = (float*)d_out;
    float* Kk  = (float*)d_ws;   // needs 50*2048*52*4 = 21.3 MB

    riccati_kernel<<<B_, 64, 0, stream>>>(C, c, F, f, Kk);
    rollout_kernel<<<B_, 128, 0, stream>>>(x0, C, c, F, f, Kk, out);
}